// Round 2
// baseline (847.285 us; speedup 1.0000x reference)
//
#include <hip/hip_runtime.h>
#include <hip/hip_bf16.h>

typedef unsigned short u16;
typedef u16   u16x4 __attribute__((ext_vector_type(4)));
typedef u16   u16x8 __attribute__((ext_vector_type(8)));
typedef short v8s   __attribute__((ext_vector_type(8)));   // 8 bf16 bits for MFMA A/B
typedef float fx4   __attribute__((ext_vector_type(4)));

#define DEVINL __device__ __forceinline__

DEVINL u16 f2bf(float x){                 // round-to-nearest-even fp32 -> bf16
    unsigned u = __float_as_uint(x);
    u = u + 0x7FFFu + ((u >> 16) & 1u);
    return (u16)(u >> 16);
}
DEVINL float bf2f(u16 h){ return __uint_as_float(((unsigned)h) << 16); }

// ---------------- conversion: z (fp32) -> Z[8192][2048] bf16 hi/lo ---------
__global__ void convZ_kernel(const float* __restrict__ zr, const float* __restrict__ zi,
                             u16* __restrict__ Zh, u16* __restrict__ Zl){
    int idx = blockIdx.x * blockDim.x + threadIdx.x;   // one float4 each
    size_t i4 = (size_t)idx * 4;
    int m = (int)(i4 >> 11);
    int c = (int)(i4 & 2047);
    const float* src = (c < 1024) ? (zr + (size_t)m*1024 + c)
                                  : (zi + (size_t)m*1024 + (c - 1024));
    fx4 v = *(const fx4*)src;
    u16x4 h, l;
#pragma unroll
    for (int j = 0; j < 4; j++){
        u16 hh = f2bf(v[j]); h[j] = hh; l[j] = f2bf(v[j] - bf2f(hh));
    }
    *(u16x4*)(Zh + i4) = h;
    *(u16x4*)(Zl + i4) = l;
}

// ------- conversion: W* (fp32 [1024][512]) -> Wt[3072][2048] bf16 hi/lo -----
// Wt row c (block b=c/512: qr,qi,kr,ki,vr,vi; j=c%512), col k (0..2047):
//   r-block: [ W_r[:,j] ; -W_i[:,j] ]     i-block: [ W_i[:,j] ; W_r[:,j] ]
__global__ void convW_kernel(const float* __restrict__ Wq_r, const float* __restrict__ Wq_i,
                             const float* __restrict__ Wk_r, const float* __restrict__ Wk_i,
                             const float* __restrict__ Wv_r, const float* __restrict__ Wv_i,
                             u16* __restrict__ Wth, u16* __restrict__ Wtl){
    __shared__ float t[32][33];
    int k0 = blockIdx.x * 32;          // 0..2047
    int c0 = blockIdx.y * 32;          // 0..3071
    int blk = c0 >> 9;  int j0 = c0 & 511;
    int pair = blk >> 1, ri = blk & 1;
    int hh = k0 >> 10;  int ks0 = k0 & 1023;
    const float* Ws[6] = {Wq_r, Wq_i, Wk_r, Wk_i, Wv_r, Wv_i};
    const float* src; float sign = 1.f;
    if (ri == 0){ if (hh == 0) src = Ws[pair*2]; else { src = Ws[pair*2+1]; sign = -1.f; } }
    else        { src = (hh == 0) ? Ws[pair*2+1] : Ws[pair*2]; }
    int tx = threadIdx.x, ty = threadIdx.y;
    for (int yy = ty; yy < 32; yy += 8)
        t[yy][tx] = src[(size_t)(ks0 + yy)*512 + j0 + tx];
    __syncthreads();
    for (int yy = ty; yy < 32; yy += 8){
        float v = sign * t[tx][yy];
        u16 h2 = f2bf(v);
        size_t o = (size_t)(c0 + yy)*2048 + k0 + tx;
        Wth[o] = h2;
        Wtl[o] = f2bf(v - bf2f(h2));
    }
}

// ---------------- Q2 = [ qi | -qr ] from C cols [512..1023],[0..511] --------
__global__ void q2_kernel(const u16* __restrict__ Chi, const u16* __restrict__ Clo,
                          u16* __restrict__ Q2h, u16* __restrict__ Q2l){
    int idx = blockIdx.x * blockDim.x + threadIdx.x;
    size_t i4 = (size_t)idx * 4;
    int m = (int)(i4 >> 10); int j = (int)(i4 & 1023);
    size_t soff; u16 x;
    if (j < 512){ soff = (size_t)m*3072 + 512 + j; x = 0; }
    else        { soff = (size_t)m*3072 + (j - 512); x = 0x8000; }
    u16x4 h = *(const u16x4*)(Chi + soff);
    u16x4 l = *(const u16x4*)(Clo + soff);
#pragma unroll
    for (int q = 0; q < 4; q++){ h[q] = (u16)(h[q] ^ x); l[q] = (u16)(l[q] ^ x); }
    *(u16x4*)(Q2h + i4) = h;
    *(u16x4*)(Q2l + i4) = l;
}

// ---------------- Vt[b][d][t] = C[(b*2048+t)*3072 + colOff + d] -------------
__global__ void vt_kernel(const u16* __restrict__ C, int colOff, u16* __restrict__ Vt){
    __shared__ u16 t[32][34];
    int t0 = blockIdx.x * 32; int d0 = blockIdx.y * 32; int b = blockIdx.z;
    int tx = threadIdx.x, ty = threadIdx.y;
    const u16* src = C + (size_t)b*2048*3072 + colOff;
    for (int yy = ty; yy < 32; yy += 8)
        t[yy][tx] = src[(size_t)(t0 + yy)*3072 + d0 + tx];
    __syncthreads();
    u16* dst = Vt + (size_t)b*512*2048;
    for (int yy = ty; yy < 32; yy += 8)
        dst[(size_t)(d0 + yy)*2048 + t0 + tx] = t[tx][yy];
}

// ---------------- hybrid scores: (|s| + a*Re/|s|)/sqrt(512), in place -------
__global__ void hybrid_kernel(float* __restrict__ Sr, const float* __restrict__ Si){
    int idx = blockIdx.x * blockDim.x + threadIdx.x;
    size_t i4 = (size_t)idx * 4;
    fx4 r  = *(fx4*)(Sr + i4);
    fx4 im = *(const fx4*)(Si + i4);
    fx4 o;
#pragma unroll
    for (int j = 0; j < 4; j++){
        float mag = sqrtf(r[j]*r[j] + im[j]*im[j]);
        float ph  = r[j] / fmaxf(mag, 1e-30f);
        o[j] = (mag + 0.3f*ph) * 0.044194173824159216f;   // 1/sqrt(512)
    }
    *(fx4*)(Sr + i4) = o;
}

// ---------------- row softmax (2048 cols), in-place + bf16 copy -------------
__global__ __launch_bounds__(256) void softmax_kernel(float* __restrict__ H, u16* __restrict__ Wbf){
    int row = blockIdx.x;
    float* p = H + (size_t)row * 2048;
    int tid = threadIdx.x;
    fx4 v[2];
    v[0] = *(fx4*)(p + tid*4);
    v[1] = *(fx4*)(p + 1024 + tid*4);
    float m = -1e30f;
#pragma unroll
    for (int i = 0; i < 2; i++)
#pragma unroll
        for (int j = 0; j < 4; j++) m = fmaxf(m, v[i][j]);
    for (int k = 1; k < 64; k <<= 1) m = fmaxf(m, __shfl_xor(m, k));
    __shared__ float sm[4], ss[4];
    int w = tid >> 6, lane = tid & 63;
    if (lane == 0) sm[w] = m;
    __syncthreads();
    m = fmaxf(fmaxf(sm[0], sm[1]), fmaxf(sm[2], sm[3]));
    float s = 0.f;
#pragma unroll
    for (int i = 0; i < 2; i++)
#pragma unroll
        for (int j = 0; j < 4; j++){ v[i][j] = __expf(v[i][j] - m); s += v[i][j]; }
    for (int k = 1; k < 64; k <<= 1) s += __shfl_xor(s, k);
    if (lane == 0) ss[w] = s;
    __syncthreads();
    s = ss[0] + ss[1] + ss[2] + ss[3];
    float inv = 1.f / s;
    u16* wb = Wbf + (size_t)row * 2048;
#pragma unroll
    for (int i = 0; i < 2; i++){
        fx4 o; u16x4 ob;
#pragma unroll
        for (int j = 0; j < 4; j++){ o[j] = v[i][j] * inv; ob[j] = f2bf(o[j]); }
        *(fx4*)(p + i*1024 + tid*4) = o;
        *(u16x4*)(wb + i*1024 + tid*4) = ob;
    }
}

// ---------------- GEMM: C = A * B^T (bf16 MFMA, optional hi/lo split) -------
// A: [M][lda] rows along K, B: [N][ldb] rows along K. M,N mult of 128, K mult of 32.
// SPLIT=1: C ~= Ah*Bh + Ah*Bl + Al*Bh (bf16x3, ~fp32 accurate)
// EPI=0: fp32 out (elem stride ostride)   EPI=1: hi/lo bf16 out
template<int SPLIT, int EPI>
__global__ __launch_bounds__(256)
void gemm_bt(const u16* __restrict__ Ah, const u16* __restrict__ Al,
             long long aBatch, int lda,
             const u16* __restrict__ Bh, const u16* __restrict__ Bl,
             long long bBatch, int ldb,
             float* __restrict__ Cf, u16* __restrict__ Ch, u16* __restrict__ Cl,
             long long cBatch, int ldc, int ostride, int nk)
{
    constexpr int LDT  = 40;          // 32 + 8 pad (u16) -> 80B rows, 16B aligned
    constexpr int TILE = 128 * LDT;
    __shared__ u16 smem[(SPLIT ? 4 : 2) * TILE];
    u16* At_h = smem;
    u16* Bt_h = smem + TILE;
    u16* At_l = SPLIT ? smem + 2*TILE : nullptr;
    u16* Bt_l = SPLIT ? smem + 3*TILE : nullptr;

    int z = blockIdx.z;
    const u16* Abase  = Ah + (size_t)(aBatch * z) + (size_t)blockIdx.y * 128 * lda;
    const u16* Bbase  = Bh + (size_t)(bBatch * z) + (size_t)blockIdx.x * 128 * ldb;
    const u16* AbaseL = SPLIT ? Al + (size_t)(aBatch * z) + (size_t)blockIdx.y * 128 * lda : nullptr;
    const u16* BbaseL = SPLIT ? Bl + (size_t)(bBatch * z) + (size_t)blockIdx.x * 128 * ldb : nullptr;

    int tid = threadIdx.x;
    int lane = tid & 63, w = tid >> 6;
    int wm = w & 1, wn = w >> 1;
    int frow = lane & 15, kg = (lane >> 4) * 8;

    fx4 acc[4][4] = {};

    for (int kt = 0; kt < nk; ++kt){
        int k0 = kt * 32;
#pragma unroll
        for (int i = 0; i < 2; i++){
            int slot = tid + i * 256;           // 512 slots = 128 rows x 4 x 16B
            int row = slot >> 2, c16 = slot & 3;
            size_t goA = (size_t)row * lda + k0 + c16 * 8;
            size_t goB = (size_t)row * ldb + k0 + c16 * 8;
            size_t lo_ = (size_t)row * LDT + c16 * 8;
            *(u16x8*)(At_h + lo_) = *(const u16x8*)(Abase + goA);
            *(u16x8*)(Bt_h + lo_) = *(const u16x8*)(Bbase + goB);
            if constexpr (SPLIT){
                *(u16x8*)(At_l + lo_) = *(const u16x8*)(AbaseL + goA);
                *(u16x8*)(Bt_l + lo_) = *(const u16x8*)(BbaseL + goB);
            }
        }
        __syncthreads();

        v8s a_h[4], b_h[4], a_l[4], b_l[4];
#pragma unroll
        for (int mi = 0; mi < 4; mi++)
            a_h[mi] = *(const v8s*)(At_h + (size_t)(wm*64 + mi*16 + frow)*LDT + kg);
#pragma unroll
        for (int ni = 0; ni < 4; ni++)
            b_h[ni] = *(const v8s*)(Bt_h + (size_t)(wn*64 + ni*16 + frow)*LDT + kg);
        if constexpr (SPLIT){
#pragma unroll
            for (int mi = 0; mi < 4; mi++)
                a_l[mi] = *(const v8s*)(At_l + (size_t)(wm*64 + mi*16 + frow)*LDT + kg);
#pragma unroll
            for (int ni = 0; ni < 4; ni++)
                b_l[ni] = *(const v8s*)(Bt_l + (size_t)(wn*64 + ni*16 + frow)*LDT + kg);
        }
#pragma unroll
        for (int mi = 0; mi < 4; mi++)
#pragma unroll
            for (int ni = 0; ni < 4; ni++){
                acc[mi][ni] = __builtin_amdgcn_mfma_f32_16x16x32_bf16(a_h[mi], b_h[ni], acc[mi][ni], 0, 0, 0);
                if constexpr (SPLIT){
                    acc[mi][ni] = __builtin_amdgcn_mfma_f32_16x16x32_bf16(a_h[mi], b_l[ni], acc[mi][ni], 0, 0, 0);
                    acc[mi][ni] = __builtin_amdgcn_mfma_f32_16x16x32_bf16(a_l[mi], b_h[ni], acc[mi][ni], 0, 0, 0);
                }
            }
        __syncthreads();
    }

    // epilogue: C/D frag layout (m89): col = lane&15, row = (lane>>4)*4 + r
    int gcol0 = blockIdx.x * 128 + wn * 64;
    int grow0 = blockIdx.y * 128 + wm * 64;
    int rgrp  = (lane >> 4) * 4;
    if constexpr (EPI == 0){
        float* Cb = Cf + (size_t)(cBatch * z);
#pragma unroll
        for (int mi = 0; mi < 4; mi++)
#pragma unroll
            for (int ni = 0; ni < 4; ni++){
                int col = gcol0 + ni*16 + frow;
#pragma unroll
                for (int r = 0; r < 4; r++){
                    int row = grow0 + mi*16 + rgrp + r;
                    Cb[((size_t)row * ldc + col) * (size_t)ostride] = acc[mi][ni][r];
                }
            }
    } else {
        u16* Chb = Ch + (size_t)(cBatch * z);
        u16* Clb = Cl + (size_t)(cBatch * z);
#pragma unroll
        for (int mi = 0; mi < 4; mi++)
#pragma unroll
            for (int ni = 0; ni < 4; ni++){
                int col = gcol0 + ni*16 + frow;
#pragma unroll
                for (int r = 0; r < 4; r++){
                    int row = grow0 + mi*16 + rgrp + r;
                    float v = acc[mi][ni][r];
                    u16 hh = f2bf(v);
                    size_t o = (size_t)row * ldc + col;
                    Chb[o] = hh;
                    Clb[o] = f2bf(v - bf2f(hh));
                }
            }
    }
}

// ---------------------------------------------------------------------------
extern "C" void kernel_launch(void* const* d_in, const int* in_sizes, int n_in,
                              void* d_out, int out_size, void* d_ws, size_t ws_size,
                              hipStream_t stream)
{
    const float* zr   = (const float*)d_in[0];
    const float* zi   = (const float*)d_in[1];
    const float* Wq_r = (const float*)d_in[2];
    const float* Wq_i = (const float*)d_in[3];
    const float* Wk_r = (const float*)d_in[4];
    const float* Wk_i = (const float*)d_in[5];
    const float* Wv_r = (const float*)d_in[6];
    const float* Wv_i = (const float*)d_in[7];

    constexpr long long Bn = 4, S = 2048, DI = 512;
    // ---- workspace layout (peak ~216 MiB) ----
    char* ws = (char*)d_ws;
    u16* Chi = (u16*)ws;                       // [8192][3072] bf16 hi
    u16* Clo = Chi + 25165824;                 // lo
    u16* Q2h = Clo + 25165824;                 // [8192][1024]
    u16* Q2l = Q2h + 8388608;
    char* ws2 = ws + 134217728;                // Z/Wt region; reused later
    u16* Zh  = (u16*)ws2;                      // [8192][2048]
    u16* Zl  = Zh + 16777216;
    u16* Wth = Zl + 16777216;                  // [3072][2048]
    u16* Wtl = Wth + 6291456;
    float* Si = (float*)ws2;                   // reuse Z/Wt after proj: [4][2048][2048]
    u16* Vt  = (u16*)(ws2 + 67108864);         // [4][512][2048]
    u16* Vti = Vt + 4194304;
    u16* Wbf = (u16*)ws;                       // reuse C region after scores+Vt: [8192][2048]

    long long attn_elems = Bn * S * S;                       // 16777216
    bool interleaved = ((long long)out_size - attn_elems) == 2LL * Bn * S * DI;
    float* outP = (float*)d_out;
    float* attn = outP + ((long long)out_size - attn_elems); // Sr scratch -> weights

    dim3 b256(256);
    convZ_kernel<<<16384, b256, 0, stream>>>(zr, zi, Zh, Zl);
    convW_kernel<<<dim3(64, 96), dim3(32, 8), 0, stream>>>(Wq_r, Wq_i, Wk_r, Wk_i, Wv_r, Wv_i, Wth, Wtl);

    // proj: C[8192][3072] = Z * Wt^T   (split, hi/lo out)
    gemm_bt<1,1><<<dim3(24, 64, 1), b256, 0, stream>>>(
        Zh, Zl, 0, 2048,
        Wth, Wtl, 0, 2048,
        nullptr, Chi, Clo, 0, 3072, 1, 2048/32);

    q2_kernel<<<8192, b256, 0, stream>>>(Chi, Clo, Q2h, Q2l);

    // Sr = [qr|qi]*[kr|ki]^T per batch -> attn region (scratch)
    gemm_bt<1,0><<<dim3(16, 16, 4), b256, 0, stream>>>(
        Chi, Clo, 2048LL*3072, 3072,
        Chi + 1024, Clo + 1024, 2048LL*3072, 3072,
        attn, nullptr, nullptr, 2048LL*2048, 2048, 1, 1024/32);

    // Si = [qi|-qr]*[kr|ki]^T per batch -> ws
    gemm_bt<1,0><<<dim3(16, 16, 4), b256, 0, stream>>>(
        Q2h, Q2l, 2048LL*1024, 1024,
        Chi + 1024, Clo + 1024, 2048LL*3072, 3072,
        Si, nullptr, nullptr, 2048LL*2048, 2048, 1, 1024/32);

    // Vt: vr (cols 2048..2559) transposed per batch
    vt_kernel<<<dim3(64, 16, 4), dim3(32, 8), 0, stream>>>(Chi, 2048, Vt);
    if (interleaved)
        vt_kernel<<<dim3(64, 16, 4), dim3(32, 8), 0, stream>>>(Chi, 2560, Vti);

    hybrid_kernel<<<16384, b256, 0, stream>>>(attn, Si);
    softmax_kernel<<<8192, b256, 0, stream>>>(attn, Wbf);

    // PV: out[s][d] = sum_t W[s][t] * vr[t][d]  == Wbf * Vt^T
    if (!interleaved){
        gemm_bt<0,0><<<dim3(4, 16, 4), b256, 0, stream>>>(
            Wbf, nullptr, 2048LL*2048, 2048,
            Vt, nullptr, 512LL*2048, 2048,
            outP, nullptr, nullptr, 2048LL*512, 512, 1, 2048/32);
    } else {
        gemm_bt<0,0><<<dim3(4, 16, 4), b256, 0, stream>>>(
            Wbf, nullptr, 2048LL*2048, 2048,
            Vt, nullptr, 512LL*2048, 2048,
            outP, nullptr, nullptr, 2048LL*512*2, 512, 2, 2048/32);
        gemm_bt<0,0><<<dim3(4, 16, 4), b256, 0, stream>>>(
            Wbf, nullptr, 2048LL*2048, 2048,
            Vti, nullptr, 512LL*2048, 2048,
            outP + 1, nullptr, nullptr, 2048LL*512*2, 512, 2, 2048/32);
    }
    (void)in_sizes; (void)n_in; (void)ws_size;
}

// Round 3
// 714.708 us; speedup vs baseline: 1.1855x; 1.1855x over previous
//
#include <hip/hip_runtime.h>
#include <hip/hip_bf16.h>

typedef unsigned short u16;
typedef u16   u16x4 __attribute__((ext_vector_type(4)));
typedef u16   u16x8 __attribute__((ext_vector_type(8)));
typedef short v8s   __attribute__((ext_vector_type(8)));   // 8 bf16 bits for MFMA A/B
typedef float fx4   __attribute__((ext_vector_type(4)));

#define DEVINL __device__ __forceinline__

DEVINL u16 f2bf(float x){                 // round-to-nearest-even fp32 -> bf16
    unsigned u = __float_as_uint(x);
    u = u + 0x7FFFu + ((u >> 16) & 1u);
    return (u16)(u >> 16);
}
DEVINL float bf2f(u16 h){ return __uint_as_float(((unsigned)h) << 16); }

// async global -> LDS, 16B per lane (dest = wave-uniform base + lane*16)
DEVINL void gload16(const u16* g, u16* l){
    __builtin_amdgcn_global_load_lds(
        (const __attribute__((address_space(1))) void*)g,
        (__attribute__((address_space(3))) void*)l, 16, 0, 0);
}

// ---------------- conversion: z (fp32) -> Z[8192][2048] bf16 hi/lo ---------
__global__ void convZ_kernel(const float* __restrict__ zr, const float* __restrict__ zi,
                             u16* __restrict__ Zh, u16* __restrict__ Zl){
    int idx = blockIdx.x * blockDim.x + threadIdx.x;   // one float4 each
    size_t i4 = (size_t)idx * 4;
    int m = (int)(i4 >> 11);
    int c = (int)(i4 & 2047);
    const float* src = (c < 1024) ? (zr + (size_t)m*1024 + c)
                                  : (zi + (size_t)m*1024 + (c - 1024));
    fx4 v = *(const fx4*)src;
    u16x4 h, l;
#pragma unroll
    for (int j = 0; j < 4; j++){
        u16 hh = f2bf(v[j]); h[j] = hh; l[j] = f2bf(v[j] - bf2f(hh));
    }
    *(u16x4*)(Zh + i4) = h;
    *(u16x4*)(Zl + i4) = l;
}

// ------- conversion: W* (fp32 [1024][512]) -> Wt[3072][2048] bf16 hi/lo -----
__global__ void convW_kernel(const float* __restrict__ Wq_r, const float* __restrict__ Wq_i,
                             const float* __restrict__ Wk_r, const float* __restrict__ Wk_i,
                             const float* __restrict__ Wv_r, const float* __restrict__ Wv_i,
                             u16* __restrict__ Wth, u16* __restrict__ Wtl){
    __shared__ float t[32][33];
    int k0 = blockIdx.x * 32;          // 0..2047
    int c0 = blockIdx.y * 32;          // 0..3071
    int blk = c0 >> 9;  int j0 = c0 & 511;
    int pair = blk >> 1, ri = blk & 1;
    int hh = k0 >> 10;  int ks0 = k0 & 1023;
    const float* Ws[6] = {Wq_r, Wq_i, Wk_r, Wk_i, Wv_r, Wv_i};
    const float* src; float sign = 1.f;
    if (ri == 0){ if (hh == 0) src = Ws[pair*2]; else { src = Ws[pair*2+1]; sign = -1.f; } }
    else        { src = (hh == 0) ? Ws[pair*2+1] : Ws[pair*2]; }
    int tx = threadIdx.x, ty = threadIdx.y;
    for (int yy = ty; yy < 32; yy += 8)
        t[yy][tx] = src[(size_t)(ks0 + yy)*512 + j0 + tx];
    __syncthreads();
    for (int yy = ty; yy < 32; yy += 8){
        float v = sign * t[tx][yy];
        u16 h2 = f2bf(v);
        size_t o = (size_t)(c0 + yy)*2048 + k0 + tx;
        Wth[o] = h2;
        Wtl[o] = f2bf(v - bf2f(h2));
    }
}

// ---------------- Q2 = [ qi | -qr ] from C cols [512..1023],[0..511] --------
__global__ void q2_kernel(const u16* __restrict__ Chi, const u16* __restrict__ Clo,
                          u16* __restrict__ Q2h, u16* __restrict__ Q2l){
    int idx = blockIdx.x * blockDim.x + threadIdx.x;
    size_t i4 = (size_t)idx * 4;
    int m = (int)(i4 >> 10); int j = (int)(i4 & 1023);
    size_t soff; u16 x;
    if (j < 512){ soff = (size_t)m*3072 + 512 + j; x = 0; }
    else        { soff = (size_t)m*3072 + (j - 512); x = 0x8000; }
    u16x4 h = *(const u16x4*)(Chi + soff);
    u16x4 l = *(const u16x4*)(Clo + soff);
#pragma unroll
    for (int q = 0; q < 4; q++){ h[q] = (u16)(h[q] ^ x); l[q] = (u16)(l[q] ^ x); }
    *(u16x4*)(Q2h + i4) = h;
    *(u16x4*)(Q2l + i4) = l;
}

// ---------------- Vt[b][d][t] = C[(b*2048+t)*3072 + colOff + d] -------------
__global__ void vt_kernel(const u16* __restrict__ C, int colOff, u16* __restrict__ Vt){
    __shared__ u16 t[32][34];
    int t0 = blockIdx.x * 32; int d0 = blockIdx.y * 32; int b = blockIdx.z;
    int tx = threadIdx.x, ty = threadIdx.y;
    const u16* src = C + (size_t)b*2048*3072 + colOff;
    for (int yy = ty; yy < 32; yy += 8)
        t[yy][tx] = src[(size_t)(t0 + yy)*3072 + d0 + tx];
    __syncthreads();
    u16* dst = Vt + (size_t)b*512*2048;
    for (int yy = ty; yy < 32; yy += 8)
        dst[(size_t)(d0 + yy)*2048 + t0 + tx] = t[tx][yy];
}

// ------ fused hybrid + row softmax (2048 cols), writes fp32 + bf16 ----------
__global__ __launch_bounds__(256)
void softmax_kernel(float* __restrict__ H, const float* __restrict__ SiP, u16* __restrict__ Wbf){
    int row = blockIdx.x;
    float* p = H + (size_t)row * 2048;
    const float* q = SiP + (size_t)row * 2048;
    int tid = threadIdx.x;
    fx4 v[2];
#pragma unroll
    for (int i = 0; i < 2; i++){
        fx4 sr = *(fx4*)(p + i*1024 + tid*4);
        fx4 si = *(const fx4*)(q + i*1024 + tid*4);
#pragma unroll
        for (int j = 0; j < 4; j++){
            float mag = sqrtf(sr[j]*sr[j] + si[j]*si[j]);
            float ph  = sr[j] / fmaxf(mag, 1e-30f);
            v[i][j] = (mag + 0.3f*ph) * 0.044194173824159216f;   // 1/sqrt(512)
        }
    }
    float m = -1e30f;
#pragma unroll
    for (int i = 0; i < 2; i++)
#pragma unroll
        for (int j = 0; j < 4; j++) m = fmaxf(m, v[i][j]);
    for (int k = 1; k < 64; k <<= 1) m = fmaxf(m, __shfl_xor(m, k));
    __shared__ float sm[4], ss[4];
    int w = tid >> 6, lane = tid & 63;
    if (lane == 0) sm[w] = m;
    __syncthreads();
    m = fmaxf(fmaxf(sm[0], sm[1]), fmaxf(sm[2], sm[3]));
    float s = 0.f;
#pragma unroll
    for (int i = 0; i < 2; i++)
#pragma unroll
        for (int j = 0; j < 4; j++){ v[i][j] = __expf(v[i][j] - m); s += v[i][j]; }
    for (int k = 1; k < 64; k <<= 1) s += __shfl_xor(s, k);
    if (lane == 0) ss[w] = s;
    __syncthreads();
    s = ss[0] + ss[1] + ss[2] + ss[3];
    float inv = 1.f / s;
    u16* wb = Wbf + (size_t)row * 2048;
#pragma unroll
    for (int i = 0; i < 2; i++){
        fx4 o; u16x4 ob;
#pragma unroll
        for (int j = 0; j < 4; j++){ o[j] = v[i][j] * inv; ob[j] = f2bf(o[j]); }
        *(fx4*)(p + i*1024 + tid*4) = o;
        *(u16x4*)(wb + i*1024 + tid*4) = ob;
    }
}

// ---------------- GEMM: C = A * B^T (bf16 MFMA, optional hi/lo split) -------
// A: [M][lda] rows along K, B: [N][ldb] rows along K. M,N mult of 128, K mult of 64.
// BK=64; LDS tiles [128 rows][64 u16] (128B rows), XOR-swizzled:
//   phys 16B-slot = logical_slot ^ (row & 7)  (involution; linear LDS dest for
//   global_load_lds + inverse-swizzled GLOBAL source + swizzled ds_read)
// SPLIT=1: C ~= Ah*Bh + Ah*Bl + Al*Bh (bf16x3, ~fp32 accurate)
// EPI=0: fp32 out (elem stride ostride)   EPI=1: hi/lo bf16 out
template<int SPLIT, int EPI>
__global__ __launch_bounds__(256, 2)
void gemm_bt(const u16* __restrict__ Ah, const u16* __restrict__ Al,
             long long aBatch, int lda,
             const u16* __restrict__ Bh, const u16* __restrict__ Bl,
             long long bBatch, int ldb,
             float* __restrict__ Cf, u16* __restrict__ Ch, u16* __restrict__ Cl,
             long long cBatch, int ldc, int ostride, int nk)
{
    constexpr int NT = SPLIT ? 4 : 2;           // tiles: Ah, Bh, (Al, Bl)
    __shared__ u16 smem[NT * 8192];             // 16KB per tile

    int z = blockIdx.z;
    const u16* Ab  = Ah + (size_t)(aBatch * z) + (size_t)blockIdx.y * 128 * lda;
    const u16* Bb  = Bh + (size_t)(bBatch * z) + (size_t)blockIdx.x * 128 * ldb;

    int tid = threadIdx.x;
    int lane = tid & 63, w = tid >> 6;
    int wm = w & 1, wn = w >> 1;
    int frow = lane & 15, g = lane >> 4;

    // ---- staging addressing: wave w stages rows [w*32, w*32+32), 8 rows/call
    // lane l writes LDS phys bytes base+l*16 -> row = w*32+c*8+(l>>3), phys slot l&7
    // logical slot = (l&7) ^ (l>>3)  (row&7 == l>>3 here)
    int srow = w * 32 + (lane >> 3);
    int slog = (lane & 7) ^ (lane >> 3);
    const u16* pA  = Ab + (size_t)srow * lda + slog * 8;
    const u16* pB  = Bb + (size_t)srow * ldb + slog * 8;
    const u16* pAl = nullptr; const u16* pBl = nullptr;
    if constexpr (SPLIT){
        pAl = Al + (size_t)(aBatch * z) + (size_t)blockIdx.y * 128 * lda + (size_t)srow * lda + slog * 8;
        pBl = Bl + (size_t)(bBatch * z) + (size_t)blockIdx.x * 128 * ldb + (size_t)srow * ldb + slog * 8;
    }
    u16* ldsA  = smem + w * 2048;               // + c*512 per call (u16 units)
    u16* ldsB  = smem + 8192 + w * 2048;
    u16* ldsAl = smem + 16384 + w * 2048;
    u16* ldsBl = smem + 24576 + w * 2048;

    fx4 acc[4][4] = {};

    for (int kt = 0; kt < nk; ++kt){
#pragma unroll
        for (int c = 0; c < 4; c++){
            size_t ga = (size_t)c * 8 * lda;
            size_t gb = (size_t)c * 8 * ldb;
            gload16(pA + ga, ldsA + c * 512);
            gload16(pB + gb, ldsB + c * 512);
            if constexpr (SPLIT){
                gload16(pAl + ga, ldsAl + c * 512);
                gload16(pBl + gb, ldsBl + c * 512);
            }
        }
        __syncthreads();   // drains vmcnt (compiler emits s_waitcnt vmcnt(0) before s_barrier)

#pragma unroll
        for (int s = 0; s < 2; s++){
            int ko = ((g + 4*s) ^ (frow & 7)) * 8;   // swizzled 16B slot within 128B row
            v8s a_h[4], b_h[4];
#pragma unroll
            for (int mi = 0; mi < 4; mi++)
                a_h[mi] = *(const v8s*)(smem + (wm*64 + mi*16 + frow)*64 + ko);
#pragma unroll
            for (int ni = 0; ni < 4; ni++)
                b_h[ni] = *(const v8s*)(smem + 8192 + (wn*64 + ni*16 + frow)*64 + ko);
            if constexpr (SPLIT){
                v8s a_l[4], b_l[4];
#pragma unroll
                for (int mi = 0; mi < 4; mi++)
                    a_l[mi] = *(const v8s*)(smem + 16384 + (wm*64 + mi*16 + frow)*64 + ko);
#pragma unroll
                for (int ni = 0; ni < 4; ni++)
                    b_l[ni] = *(const v8s*)(smem + 24576 + (wn*64 + ni*16 + frow)*64 + ko);
#pragma unroll
                for (int mi = 0; mi < 4; mi++)
#pragma unroll
                    for (int ni = 0; ni < 4; ni++){
                        acc[mi][ni] = __builtin_amdgcn_mfma_f32_16x16x32_bf16(a_h[mi], b_h[ni], acc[mi][ni], 0, 0, 0);
                        acc[mi][ni] = __builtin_amdgcn_mfma_f32_16x16x32_bf16(a_h[mi], b_l[ni], acc[mi][ni], 0, 0, 0);
                        acc[mi][ni] = __builtin_amdgcn_mfma_f32_16x16x32_bf16(a_l[mi], b_h[ni], acc[mi][ni], 0, 0, 0);
                    }
            } else {
#pragma unroll
                for (int mi = 0; mi < 4; mi++)
#pragma unroll
                    for (int ni = 0; ni < 4; ni++)
                        acc[mi][ni] = __builtin_amdgcn_mfma_f32_16x16x32_bf16(a_h[mi], b_h[ni], acc[mi][ni], 0, 0, 0);
            }
        }
        __syncthreads();   // protect LDS before next-tile overwrite
        pA += 64; pB += 64;
        if constexpr (SPLIT){ pAl += 64; pBl += 64; }
    }

    // epilogue: C/D frag layout (m89): col = lane&15, row = (lane>>4)*4 + r
    int gcol0 = blockIdx.x * 128 + wn * 64;
    int grow0 = blockIdx.y * 128 + wm * 64;
    int rgrp  = (lane >> 4) * 4;
    if constexpr (EPI == 0){
        float* Cb = Cf + (size_t)(cBatch * z);
#pragma unroll
        for (int mi = 0; mi < 4; mi++)
#pragma unroll
            for (int ni = 0; ni < 4; ni++){
                int col = gcol0 + ni*16 + frow;
#pragma unroll
                for (int r = 0; r < 4; r++){
                    int row = grow0 + mi*16 + rgrp + r;
                    Cb[((size_t)row * ldc + col) * (size_t)ostride] = acc[mi][ni][r];
                }
            }
    } else {
        u16* Chb = Ch + (size_t)(cBatch * z);
        u16* Clb = Cl + (size_t)(cBatch * z);
#pragma unroll
        for (int mi = 0; mi < 4; mi++)
#pragma unroll
            for (int ni = 0; ni < 4; ni++){
                int col = gcol0 + ni*16 + frow;
#pragma unroll
                for (int r = 0; r < 4; r++){
                    int row = grow0 + mi*16 + rgrp + r;
                    float v = acc[mi][ni][r];
                    u16 hh = f2bf(v);
                    size_t o = (size_t)row * ldc + col;
                    Chb[o] = hh;
                    Clb[o] = f2bf(v - bf2f(hh));
                }
            }
    }
}

// ---------------------------------------------------------------------------
extern "C" void kernel_launch(void* const* d_in, const int* in_sizes, int n_in,
                              void* d_out, int out_size, void* d_ws, size_t ws_size,
                              hipStream_t stream)
{
    const float* zr   = (const float*)d_in[0];
    const float* zi   = (const float*)d_in[1];
    const float* Wq_r = (const float*)d_in[2];
    const float* Wq_i = (const float*)d_in[3];
    const float* Wk_r = (const float*)d_in[4];
    const float* Wk_i = (const float*)d_in[5];
    const float* Wv_r = (const float*)d_in[6];
    const float* Wv_i = (const float*)d_in[7];

    constexpr long long Bn = 4, S = 2048, DI = 512;
    // ---- workspace layout (peak ~216 MiB) ----
    char* ws = (char*)d_ws;
    u16* Chi = (u16*)ws;                       // [8192][3072] bf16 hi
    u16* Clo = Chi + 25165824;                 // lo
    u16* Q2h = Clo + 25165824;                 // [8192][1024]
    u16* Q2l = Q2h + 8388608;
    char* ws2 = ws + 134217728;                // Z/Wt region; reused later
    u16* Zh  = (u16*)ws2;                      // [8192][2048]
    u16* Zl  = Zh + 16777216;
    u16* Wth = Zl + 16777216;                  // [3072][2048]
    u16* Wtl = Wth + 6291456;
    float* Si = (float*)ws2;                   // reuse Z/Wt after proj: [4][2048][2048]
    u16* Vt  = (u16*)(ws2 + 67108864);         // [4][512][2048]
    u16* Vti = Vt + 4194304;
    u16* Wbf = (u16*)ws;                       // reuse C region after scores+Vt: [8192][2048]

    long long attn_elems = Bn * S * S;                       // 16777216
    bool interleaved = ((long long)out_size - attn_elems) == 2LL * Bn * S * DI;
    float* outP = (float*)d_out;
    float* attn = outP + ((long long)out_size - attn_elems); // Sr scratch -> weights

    dim3 b256(256);
    convZ_kernel<<<16384, b256, 0, stream>>>(zr, zi, Zh, Zl);
    convW_kernel<<<dim3(64, 96), dim3(32, 8), 0, stream>>>(Wq_r, Wq_i, Wk_r, Wk_i, Wv_r, Wv_i, Wth, Wtl);

    // proj: C[8192][3072] = Z * Wt^T   (split, hi/lo out)
    gemm_bt<1,1><<<dim3(24, 64, 1), b256, 0, stream>>>(
        Zh, Zl, 0, 2048,
        Wth, Wtl, 0, 2048,
        nullptr, Chi, Clo, 0, 3072, 1, 2048/64);

    q2_kernel<<<8192, b256, 0, stream>>>(Chi, Clo, Q2h, Q2l);

    // Sr = [qr|qi]*[kr|ki]^T per batch -> attn region (scratch)
    gemm_bt<1,0><<<dim3(16, 16, 4), b256, 0, stream>>>(
        Chi, Clo, 2048LL*3072, 3072,
        Chi + 1024, Clo + 1024, 2048LL*3072, 3072,
        attn, nullptr, nullptr, 2048LL*2048, 2048, 1, 1024/64);

    // Si = [qi|-qr]*[kr|ki]^T per batch -> ws
    gemm_bt<1,0><<<dim3(16, 16, 4), b256, 0, stream>>>(
        Q2h, Q2l, 2048LL*1024, 1024,
        Chi + 1024, Clo + 1024, 2048LL*3072, 3072,
        Si, nullptr, nullptr, 2048LL*2048, 2048, 1, 1024/64);

    // Vt: vr (cols 2048..2559) transposed per batch
    vt_kernel<<<dim3(64, 16, 4), dim3(32, 8), 0, stream>>>(Chi, 2048, Vt);
    if (interleaved)
        vt_kernel<<<dim3(64, 16, 4), dim3(32, 8), 0, stream>>>(Chi, 2560, Vti);

    softmax_kernel<<<8192, b256, 0, stream>>>(attn, Si, Wbf);

    // PV: out[s][d] = sum_t W[s][t] * vr[t][d]  == Wbf * Vt^T
    if (!interleaved){
        gemm_bt<0,0><<<dim3(4, 16, 4), b256, 0, stream>>>(
            Wbf, nullptr, 2048LL*2048, 2048,
            Vt, nullptr, 512LL*2048, 2048,
            outP, nullptr, nullptr, 2048LL*512, 512, 1, 2048/64);
    } else {
        gemm_bt<0,0><<<dim3(4, 16, 4), b256, 0, stream>>>(
            Wbf, nullptr, 2048LL*2048, 2048,
            Vt, nullptr, 512LL*2048, 2048,
            outP, nullptr, nullptr, 2048LL*512*2, 512, 2, 2048/64);
        gemm_bt<0,0><<<dim3(4, 16, 4), b256, 0, stream>>>(
            Wbf, nullptr, 2048LL*2048, 2048,
            Vti, nullptr, 512LL*2048, 2048,
            outP + 1, nullptr, nullptr, 2048LL*512*2, 512, 2, 2048/64);
    }
    (void)in_sizes; (void)n_in; (void)ws_size;
}